// Round 11
// baseline (476.404 us; speedup 1.0000x reference)
//
#include <hip/hip_runtime.h>
#include <hip/hip_bf16.h>

// SimpleMoE: B=2,S=2048 -> 4096 tokens, DIM=1024, FF=4096, E=8, top-2 routing.
// Round 11: 256x256-tile 8-wave GEMMs (BK=32, 3-buffer, 2-K-tile lookahead,
// vmcnt(4), ONE barrier per K-tile, 32 MFMA/barrier, setprio around MFMA).
// Keeps: XCD expert pinning, r8 XOR swizzle (0 bank conflicts), split-K=2
// private-P gemm2, LDS-tiled weight transposes, gate-fused xconv.

typedef __attribute__((ext_vector_type(8))) short bf16x8;
typedef __attribute__((ext_vector_type(4))) float f32x4;

#define MFMA16(a, b, c) __builtin_amdgcn_mfma_f32_16x16x32_bf16((a), (b), (c), 0, 0, 0)

__device__ __forceinline__ unsigned short f2bf(float f) {
  unsigned u = __builtin_bit_cast(unsigned, f);
  u += 0x7FFFu + ((u >> 16) & 1u);
  return (unsigned short)(u >> 16);
}

__device__ __forceinline__ void gload_lds16(const void* g, void* l) {
  __builtin_amdgcn_global_load_lds(
      (const __attribute__((address_space(1))) unsigned int*)g,
      (__attribute__((address_space(3))) unsigned int*)l, 16, 0, 0);
}

__device__ __forceinline__ bf16x8 ldsr128(const void* p) {
  bf16x8 r;
  unsigned a = (unsigned)(unsigned long long)p;
  asm volatile("ds_read_b128 %0, %1" : "=v"(r) : "v"(a));
  return r;
}

// ---------------- gate: logits (fp64), softmax, top-2, counts; also x->bf16 --
__global__ __launch_bounds__(256) void gate_kernel(
    const float* __restrict__ x, const float* __restrict__ Wg,
    const float* __restrict__ bg, int* __restrict__ tok_e,
    float* __restrict__ tok_w, int* __restrict__ counts,
    unsigned short* __restrict__ xb) {
  const int wave = threadIdx.x >> 6;
  const int lane = threadIdx.x & 63;
  const int t = blockIdx.x * 4 + wave;
  const float* xr = x + (size_t)t * 1024;
  unsigned short* xrow = xb + (size_t)t * 1024;
  double acc[8] = {0, 0, 0, 0, 0, 0, 0, 0};
  for (int i = 0; i < 16; ++i) {
    const int d = i * 64 + lane;
    const float vx = xr[d];
    xrow[d] = f2bf(vx);
    const double xv = (double)vx;
    const float* wr = Wg + d * 8;
#pragma unroll
    for (int e = 0; e < 8; ++e) acc[e] += xv * (double)wr[e];
  }
#pragma unroll
  for (int e = 0; e < 8; ++e) {
    double v = acc[e];
#pragma unroll
    for (int off = 32; off > 0; off >>= 1) v += __shfl_xor(v, off, 64);
    acc[e] = v + (double)bg[e];
  }
  if (lane == 0) {
    int e0 = 0;
#pragma unroll
    for (int e = 1; e < 8; ++e)
      if (acc[e] > acc[e0]) e0 = e;
    int e1 = (e0 == 0) ? 1 : 0;
#pragma unroll
    for (int e = 0; e < 8; ++e) {
      if (e != e0 && acc[e] > acc[e1]) e1 = e;
    }
    const double m = acc[e0];
    double s = 0.0;
#pragma unroll
    for (int e = 0; e < 8; ++e) s += exp(acc[e] - m);
    const double p0 = exp(acc[e0] - m) / s;
    const double p1 = exp(acc[e1] - m) / s;
    const double den = p0 + p1 + 1e-9;
    tok_e[2 * t] = e0;
    tok_e[2 * t + 1] = e1;
    tok_w[2 * t] = (float)(p0 / den);
    tok_w[2 * t + 1] = (float)(p1 / den);
    atomicAdd(&counts[e0], 1);
    atomicAdd(&counts[e1], 1);
  }
}

// ---------------- scan + scatter fused (single block) ----------------
__global__ __launch_bounds__(256) void scan_scatter_kernel(
    const int* __restrict__ counts, const int* __restrict__ tok_e,
    int* __restrict__ offsets, int* __restrict__ pair_token,
    int* __restrict__ tok_slot) {
  __shared__ int scur[8];
  const int tid = threadIdx.x;
  if (tid == 0) {
    int s = 0;
    for (int e = 0; e < 8; ++e) {
      offsets[e] = s;
      scur[e] = s;
      s += counts[e];
    }
  }
  __syncthreads();
  for (int t = tid; t < 4096; t += 256) {
#pragma unroll
    for (int j = 0; j < 2; ++j) {
      const int e = tok_e[2 * t + j];
      const int slot = atomicAdd(&scur[e], 1);
      pair_token[slot] = t;
      tok_slot[2 * t + j] = slot;
    }
  }
}

// -------- W1[e][k][f] -> W1t[e][f-f0][k] (bf16), LDS-tiled ----------------
__global__ __launch_bounds__(256) void transW1_kernel(
    const float* __restrict__ W1, unsigned short* __restrict__ W1t, int FC,
    int f0) {
  const int e = blockIdx.z;
  const int fb = blockIdx.x * 32;
  const int kb = blockIdx.y * 512;
  __shared__ __align__(16) unsigned short T[32][520];

  const int tid = threadIdx.x;
  const int fo = tid & 31;
  const int kg = tid >> 5;
  const float* src =
      W1 + ((size_t)e * 1024 + kb + kg * 64) * 4096 + f0 + fb + fo;
#pragma unroll
  for (int i8 = 0; i8 < 8; ++i8) {
    uint4 pk;
    const float* s8 = src + (size_t)i8 * 8 * 4096;
    pk.x = (unsigned)f2bf(s8[0]) | ((unsigned)f2bf(s8[(size_t)4096]) << 16);
    pk.y = (unsigned)f2bf(s8[(size_t)2 * 4096]) |
           ((unsigned)f2bf(s8[(size_t)3 * 4096]) << 16);
    pk.z = (unsigned)f2bf(s8[(size_t)4 * 4096]) |
           ((unsigned)f2bf(s8[(size_t)5 * 4096]) << 16);
    pk.w = (unsigned)f2bf(s8[(size_t)6 * 4096]) |
           ((unsigned)f2bf(s8[(size_t)7 * 4096]) << 16);
    *(uint4*)&T[fo][kg * 64 + i8 * 8] = pk;
  }
  __syncthreads();
  const int fr = tid >> 3;
  const int sg = tid & 7;
  unsigned short* dst = W1t + ((size_t)e * FC + fb + fr) * 1024 + kb;
#pragma unroll
  for (int j = 0; j < 8; ++j) {
    const int c = sg + j * 8;
    *(uint4*)(dst + c * 8) = *(const uint4*)&T[fr][c * 8];
  }
}

// -------- W2[e][f][d] -> W2t[e][d][f-f0] (bf16), LDS-tiled ----------------
__global__ __launch_bounds__(256) void transW2_kernel(
    const float* __restrict__ W2, unsigned short* __restrict__ W2t, int FC,
    int f0) {
  const int e = blockIdx.z;
  const int db = blockIdx.x * 32;
  const int fb = blockIdx.y * 256;
  __shared__ __align__(16) unsigned short T[32][264];

  const int tid = threadIdx.x;
  const int dd = tid & 31;
  const int fg = tid >> 5;
  const float* src =
      W2 + ((size_t)e * 4096 + f0 + fb + fg * 32) * 1024 + db + dd;
#pragma unroll
  for (int i8 = 0; i8 < 4; ++i8) {
    uint4 pk;
    const float* s8 = src + (size_t)i8 * 8 * 1024;
    pk.x = (unsigned)f2bf(s8[0]) | ((unsigned)f2bf(s8[1024]) << 16);
    pk.y = (unsigned)f2bf(s8[2048]) | ((unsigned)f2bf(s8[3072]) << 16);
    pk.z = (unsigned)f2bf(s8[4096]) | ((unsigned)f2bf(s8[5120]) << 16);
    pk.w = (unsigned)f2bf(s8[6144]) | ((unsigned)f2bf(s8[7168]) << 16);
    *(uint4*)&T[dd][fg * 32 + i8 * 8] = pk;
  }
  __syncthreads();
  const int dr = tid >> 3;
  const int sg = tid & 7;
  unsigned short* dst = W2t + ((size_t)e * 1024 + db + dr) * FC + fb;
#pragma unroll
  for (int j = 0; j < 4; ++j) {
    const int c = sg + j * 8;
    *(uint4*)(dst + c * 8) = *(const uint4*)&T[dr][c * 8];
  }
}

// ---------------- GEMM1: H[slot][n] = relu(xb[tok] @ W1t[e] + b1) -----------
// 256x256 tile, BK=32, 8 waves (2Mx4N), 3-buf 2-lookahead, 1 barrier/K-tile.
__global__ __launch_bounds__(512, 2) void gemm1_kernel(
    const unsigned short* __restrict__ xb,
    const unsigned short* __restrict__ W1t, const float* __restrict__ b1,
    const int* __restrict__ counts, const int* __restrict__ offsets,
    const int* __restrict__ pair_token, unsigned short* __restrict__ H, int FC,
    int f0) {
  const int bid = blockIdx.x;
  const int e = bid & 7;  // XCD pinning
  const int lid = bid >> 3;
  const int m0 = (lid & 15) * 256;  // m fastest: B panel L2-shared
  const int n0 = (lid >> 4) * 256;
  const int count = counts[e];
  if (m0 >= count) return;
  const int offset = offsets[e];

  __shared__ __align__(16) unsigned short Alds[3][256 * 32];
  __shared__ __align__(16) unsigned short Blds[3][256 * 32];
  __shared__ int toklds[256];

  const int tid = threadIdx.x;
  if (tid < 256) {
    int r = m0 + tid;
    if (r >= count) r = count - 1;
    toklds[tid] = pair_token[offset + r];
  }
  __syncthreads();

  const int lane = tid & 63;
  const int wave = tid >> 6;
  const int waveM = wave >> 2;
  const int waveN = wave & 3;

  // staging: thread handles 16B chunks p = tid and tid+512 (of 1024)
  const unsigned short* agp[2];
  const unsigned short* bgp[2];
  int ldso[2];
#pragma unroll
  for (int j = 0; j < 2; ++j) {
    const int p = j * 512 + tid;
    const int r = p >> 2, cp = p & 3;
    const int c = cp ^ ((r >> 1) & 3);  // source pre-swizzle
    agp[j] = xb + (size_t)toklds[r] * 1024 + c * 8;
    bgp[j] = W1t + ((size_t)e * FC + n0 + r) * 1024 + c * 8;
    ldso[j] = (j * 512 + wave * 64) * 8;  // lane-invariant dest
  }

  const int l16 = lane & 15, lk = lane >> 4;
  int rdA[8], rdB[4];
#pragma unroll
  for (int mf = 0; mf < 8; ++mf) {
    const int row = waveM * 128 + mf * 16 + l16;
    rdA[mf] = row * 32 + ((lk ^ ((row >> 1) & 3)) << 3);
  }
#pragma unroll
  for (int nf = 0; nf < 4; ++nf) {
    const int row = waveN * 64 + nf * 16 + l16;
    rdB[nf] = row * 32 + ((lk ^ ((row >> 1) & 3)) << 3);
  }

  f32x4 acc[8][4] = {};

  auto STAGE_A = [&](int kt, int buf) {
#pragma unroll
    for (int j = 0; j < 2; ++j)
      gload_lds16(agp[j] + kt * 32, &Alds[buf][ldso[j]]);
  };
  auto STAGE_B = [&](int kt, int buf) {
#pragma unroll
    for (int j = 0; j < 2; ++j)
      gload_lds16(bgp[j] + kt * 32, &Blds[buf][ldso[j]]);
  };

  const int NTk = 32;  // K = 1024
  STAGE_A(0, 0);
  STAGE_B(0, 0);
  STAGE_A(1, 1);
  STAGE_B(1, 1);
  asm volatile("s_waitcnt vmcnt(4)" ::: "memory");
  __builtin_amdgcn_s_barrier();

  for (int kt = 0; kt < NTk; ++kt) {
    const int cur = kt % 3, nxt = (kt + 2) % 3;
    bf16x8 a[8], b0, b1v, b2, b3;
#pragma unroll
    for (int mf = 0; mf < 8; ++mf) a[mf] = ldsr128(&Alds[cur][rdA[mf]]);
    b0 = ldsr128(&Blds[cur][rdB[0]]);
    b1v = ldsr128(&Blds[cur][rdB[1]]);
    if (kt + 2 < NTk) STAGE_A(kt + 2, nxt);
    asm volatile("s_waitcnt lgkmcnt(0)" ::: "memory");
    __builtin_amdgcn_sched_barrier(0);
    __builtin_amdgcn_s_setprio(1);
#pragma unroll
    for (int mf = 0; mf < 8; ++mf) {
      acc[mf][0] = MFMA16(a[mf], b0, acc[mf][0]);
      acc[mf][1] = MFMA16(a[mf], b1v, acc[mf][1]);
    }
    __builtin_amdgcn_s_setprio(0);
    __builtin_amdgcn_sched_barrier(0);
    b2 = ldsr128(&Blds[cur][rdB[2]]);
    b3 = ldsr128(&Blds[cur][rdB[3]]);
    if (kt + 2 < NTk) STAGE_B(kt + 2, nxt);
    asm volatile("s_waitcnt lgkmcnt(0)" ::: "memory");
    __builtin_amdgcn_sched_barrier(0);
    __builtin_amdgcn_s_setprio(1);
#pragma unroll
    for (int mf = 0; mf < 8; ++mf) {
      acc[mf][2] = MFMA16(a[mf], b2, acc[mf][2]);
      acc[mf][3] = MFMA16(a[mf], b3, acc[mf][3]);
    }
    __builtin_amdgcn_s_setprio(0);
    __builtin_amdgcn_sched_barrier(0);
    if (kt + 2 < NTk) {
      asm volatile("s_waitcnt vmcnt(4)" ::: "memory");  // kt+1's data landed
    } else if (kt + 1 < NTk) {
      asm volatile("s_waitcnt vmcnt(0)" ::: "memory");
    }
    if (kt + 1 < NTk) __builtin_amdgcn_s_barrier();
  }

#pragma unroll
  for (int mf = 0; mf < 8; ++mf) {
#pragma unroll
    for (int r = 0; r < 4; ++r) {
      const int rl = m0 + waveM * 128 + mf * 16 + lk * 4 + r;
      if (rl >= count) continue;
      unsigned short* hrow = H + (size_t)(offset + rl) * FC;
#pragma unroll
      for (int nf = 0; nf < 4; ++nf) {
        const int c = n0 + waveN * 64 + nf * 16 + l16;
        float v = acc[mf][nf][r] + b1[e * 4096 + f0 + c];
        hrow[c] = f2bf(v > 0.f ? v : 0.f);
      }
    }
  }
}

// ------- GEMM2: P[ks][slot][d] (+)= slice_ks(H[slot] @ W2t[e]) (+ b2) -------
__global__ __launch_bounds__(512, 2) void gemm2_kernel(
    const unsigned short* __restrict__ H,
    const unsigned short* __restrict__ W2t, const float* __restrict__ b2,
    const int* __restrict__ counts, const int* __restrict__ offsets,
    float* __restrict__ P, int FC, int firstChunk) {
  const int bid = blockIdx.x;
  const int e = bid & 7;
  const int lid = bid >> 3;
  const int m0 = (lid & 15) * 256;
  const int rest = lid >> 4;
  const int n0 = (rest & 3) * 256;  // 4 n-tiles (N=1024)
  const int ks = rest >> 2;         // K split 0/1
  const int count = counts[e];
  if (m0 >= count) return;
  const int offset = offsets[e];
  const int KS = FC / 2;
  const int kb = ks * KS;
  float* Pb = P + (size_t)ks * 8192 * 1024;

  __shared__ __align__(16) unsigned short Alds[3][256 * 32];
  __shared__ __align__(16) unsigned short Blds[3][256 * 32];

  const int tid = threadIdx.x;
  const int lane = tid & 63;
  const int wave = tid >> 6;
  const int waveM = wave >> 2;
  const int waveN = wave & 3;

  const unsigned short* agp[2];
  const unsigned short* bgp[2];
  int ldso[2];
#pragma unroll
  for (int j = 0; j < 2; ++j) {
    const int p = j * 512 + tid;
    const int r = p >> 2, cp = p & 3;
    const int c = cp ^ ((r >> 1) & 3);
    int ar = m0 + r;
    if (ar >= count) ar = count - 1;
    agp[j] = H + (size_t)(offset + ar) * FC + kb + c * 8;
    bgp[j] = W2t + ((size_t)e * 1024 + n0 + r) * FC + kb + c * 8;
    ldso[j] = (j * 512 + wave * 64) * 8;
  }

  const int l16 = lane & 15, lk = lane >> 4;
  int rdA[8], rdB[4];
#pragma unroll
  for (int mf = 0; mf < 8; ++mf) {
    const int row = waveM * 128 + mf * 16 + l16;
    rdA[mf] = row * 32 + ((lk ^ ((row >> 1) & 3)) << 3);
  }
#pragma unroll
  for (int nf = 0; nf < 4; ++nf) {
    const int row = waveN * 64 + nf * 16 + l16;
    rdB[nf] = row * 32 + ((lk ^ ((row >> 1) & 3)) << 3);
  }

  f32x4 acc[8][4] = {};

  auto STAGE_A = [&](int kt, int buf) {
#pragma unroll
    for (int j = 0; j < 2; ++j)
      gload_lds16(agp[j] + kt * 32, &Alds[buf][ldso[j]]);
  };
  auto STAGE_B = [&](int kt, int buf) {
#pragma unroll
    for (int j = 0; j < 2; ++j)
      gload_lds16(bgp[j] + kt * 32, &Blds[buf][ldso[j]]);
  };

  const int NTk = KS / 32;
  STAGE_A(0, 0);
  STAGE_B(0, 0);
  STAGE_A(1, 1);
  STAGE_B(1, 1);
  asm volatile("s_waitcnt vmcnt(4)" ::: "memory");
  __builtin_amdgcn_s_barrier();

  for (int kt = 0; kt < NTk; ++kt) {
    const int cur = kt % 3, nxt = (kt + 2) % 3;
    bf16x8 a[8], b0, b1v, b2, b3;
#pragma unroll
    for (int mf = 0; mf < 8; ++mf) a[mf] = ldsr128(&Alds[cur][rdA[mf]]);
    b0 = ldsr128(&Blds[cur][rdB[0]]);
    b1v = ldsr128(&Blds[cur][rdB[1]]);
    if (kt + 2 < NTk) STAGE_A(kt + 2, nxt);
    asm volatile("s_waitcnt lgkmcnt(0)" ::: "memory");
    __builtin_amdgcn_sched_barrier(0);
    __builtin_amdgcn_s_setprio(1);
#pragma unroll
    for (int mf = 0; mf < 8; ++mf) {
      acc[mf][0] = MFMA16(a[mf], b0, acc[mf][0]);
      acc[mf][1] = MFMA16(a[mf], b1v, acc[mf][1]);
    }
    __builtin_amdgcn_s_setprio(0);
    __builtin_amdgcn_sched_barrier(0);
    b2 = ldsr128(&Blds[cur][rdB[2]]);
    b3 = ldsr128(&Blds[cur][rdB[3]]);
    if (kt + 2 < NTk) STAGE_B(kt + 2, nxt);
    asm volatile("s_waitcnt lgkmcnt(0)" ::: "memory");
    __builtin_amdgcn_sched_barrier(0);
    __builtin_amdgcn_s_setprio(1);
#pragma unroll
    for (int mf = 0; mf < 8; ++mf) {
      acc[mf][2] = MFMA16(a[mf], b2, acc[mf][2]);
      acc[mf][3] = MFMA16(a[mf], b3, acc[mf][3]);
    }
    __builtin_amdgcn_s_setprio(0);
    __builtin_amdgcn_sched_barrier(0);
    if (kt + 2 < NTk) {
      asm volatile("s_waitcnt vmcnt(4)" ::: "memory");
    } else if (kt + 1 < NTk) {
      asm volatile("s_waitcnt vmcnt(0)" ::: "memory");
    }
    if (kt + 1 < NTk) __builtin_amdgcn_s_barrier();
  }

#pragma unroll
  for (int mf = 0; mf < 8; ++mf) {
#pragma unroll
    for (int r = 0; r < 4; ++r) {
      const int rl = m0 + waveM * 128 + mf * 16 + lk * 4 + r;
      if (rl >= count) continue;
      float* prow = Pb + (size_t)(offset + rl) * 1024;
#pragma unroll
      for (int nf = 0; nf < 4; ++nf) {
        const int c = n0 + waveN * 64 + nf * 16 + l16;
        float v = acc[mf][nf][r];
        if (ks == 0 && firstChunk) v += b2[e * 1024 + c];
        if (firstChunk)
          prow[c] = v;
        else
          prow[c] += v;
      }
    }
  }
}

// -------- combine: out[t] = w0*(P0[s0]+P1[s0]) + w1*(P0[s1]+P1[s1]) --------
__global__ __launch_bounds__(256) void combine_kernel(
    const float* __restrict__ P, const int* __restrict__ tok_slot,
    const float* __restrict__ tok_w, float* __restrict__ out) {
  const int t = blockIdx.x;
  const int d = threadIdx.x * 4;
  const int s0 = tok_slot[2 * t];
  const int s1 = tok_slot[2 * t + 1];
  const float w0 = tok_w[2 * t];
  const float w1 = tok_w[2 * t + 1];
  const float4 a0 = *(const float4*)&P[(size_t)s0 * 1024 + d];
  const float4 a1 = *(const float4*)&P[(size_t)(8192 + s0) * 1024 + d];
  const float4 c0 = *(const float4*)&P[(size_t)s1 * 1024 + d];
  const float4 c1 = *(const float4*)&P[(size_t)(8192 + s1) * 1024 + d];
  float4 r;
  r.x = w0 * (a0.x + a1.x) + w1 * (c0.x + c1.x);
  r.y = w0 * (a0.y + a1.y) + w1 * (c0.y + c1.y);
  r.z = w0 * (a0.z + a1.z) + w1 * (c0.z + c1.z);
  r.w = w0 * (a0.w + a1.w) + w1 * (c0.w + c1.w);
  *(float4*)&out[(size_t)t * 1024 + d] = r;
}

extern "C" void kernel_launch(void* const* d_in, const int* in_sizes, int n_in,
                              void* d_out, int out_size, void* d_ws,
                              size_t ws_size, hipStream_t stream) {
  const float* x = (const float*)d_in[0];
  const float* Wg = (const float*)d_in[1];
  const float* bg = (const float*)d_in[2];
  const float* W1 = (const float*)d_in[3];
  const float* b1 = (const float*)d_in[4];
  const float* W2 = (const float*)d_in[5];
  const float* b2 = (const float*)d_in[6];
  float* out = (float*)d_out;

  char* w = (char*)d_ws;
  int* counts = (int*)w;
  int* offsets = counts + 16;
  int* tok_e = (int*)(w + 1024);
  float* tok_w = (float*)(w + 1024 + 32768);
  int* pair_token = (int*)(w + 1024 + 65536);
  int* tok_slot = (int*)(w + 1024 + 98304);
  unsigned short* xb = (unsigned short*)(w + 256 * 1024);  // 8MB
  float* P = (float*)(w + 256 * 1024 + 8 * 1024 * 1024);   // 64MB (2 splits)
  char* big = w + 256 * 1024 + 8 * 1024 * 1024 + 64 * 1024 * 1024;
  const size_t avail =
      ws_size - (256 * 1024 + 8 * 1024 * 1024 + 64 * 1024 * 1024);

  // per-chunk: W1t 16384*FC + W2t 16384*FC + H 16384*FC bytes
  int FC = 4096;
  while (FC > 512 && (size_t)FC * 49152 > avail) FC >>= 1;

  unsigned short* W1t = (unsigned short*)big;
  unsigned short* W2t = W1t + (size_t)8 * FC * 1024;
  unsigned short* Hc = W2t + (size_t)8 * 1024 * FC;

  (void)hipMemsetAsync(counts, 0, 64, stream);

  gate_kernel<<<1024, 256, 0, stream>>>(x, Wg, bg, tok_e, tok_w, counts, xb);
  scan_scatter_kernel<<<1, 256, 0, stream>>>(counts, tok_e, offsets,
                                             pair_token, tok_slot);

  const int NT1 = FC / 256;  // gemm1 n-tiles per chunk
  for (int f0 = 0; f0 < 4096; f0 += FC) {
    transW1_kernel<<<dim3(FC / 32, 2, 8), 256, 0, stream>>>(W1, W1t, FC, f0);
    transW2_kernel<<<dim3(32, FC / 256, 8), 256, 0, stream>>>(W2, W2t, FC, f0);
    gemm1_kernel<<<8 * 16 * NT1, 512, 0, stream>>>(
        xb, W1t, b1, counts, offsets, pair_token, Hc, FC, f0);
    gemm2_kernel<<<8 * 16 * 4 * 2, 512, 0, stream>>>(
        Hc, W2t, b2, counts, offsets, P, FC, f0 == 0 ? 1 : 0);
  }
  combine_kernel<<<4096, 256, 0, stream>>>(P, tok_slot, tok_w, out);
}

// Round 12
// 454.372 us; speedup vs baseline: 1.0485x; 1.0485x over previous
//
#include <hip/hip_runtime.h>
#include <hip/hip_bf16.h>

// SimpleMoE: B=2,S=2048 -> 4096 tokens, DIM=1024, FF=4096, E=8, top-2 routing.
// Round 12: revert to r10 GEMM cores (best measured). Changes vs r10:
//  - gemm2 split-K removed (was neutral), P stored as bf16 (-96 MB traffic)
//  - m-fastest tile order in both GEMMs (B-panel L2 reuse, r11 FETCH evidence)
// Keeps: XCD expert pinning, XOR source-chunk swizzle (0 bank conflicts),
// counted-vmcnt 2-barrier pipeline, counted-lgkm MFMA interleave, LDS-tiled
// transposes, gate-fused xconv, fused scan+scatter.

typedef __attribute__((ext_vector_type(8))) short bf16x8;
typedef __attribute__((ext_vector_type(4))) float f32x4;

#define MFMA16(a, b, c) __builtin_amdgcn_mfma_f32_16x16x32_bf16((a), (b), (c), 0, 0, 0)

__device__ __forceinline__ unsigned short f2bf(float f) {
  unsigned u = __builtin_bit_cast(unsigned, f);
  u += 0x7FFFu + ((u >> 16) & 1u);
  return (unsigned short)(u >> 16);
}

__device__ __forceinline__ float bf2f(unsigned short s) {
  return __builtin_bit_cast(float, (unsigned)s << 16);
}

__device__ __forceinline__ void gload_lds16(const void* g, void* l) {
  __builtin_amdgcn_global_load_lds(
      (const __attribute__((address_space(1))) unsigned int*)g,
      (__attribute__((address_space(3))) unsigned int*)l, 16, 0, 0);
}

// inline-asm LDS read: keeps the compiler from serializing ds_read behind
// in-flight global_load_lds (false alias) with a vmcnt(0).
__device__ __forceinline__ bf16x8 ldsr128(const void* p) {
  bf16x8 r;
  unsigned a = (unsigned)(unsigned long long)p;
  asm volatile("ds_read_b128 %0, %1" : "=v"(r) : "v"(a));
  return r;
}

// ---------------- gate: logits (fp64), softmax, top-2, counts; also x->bf16 --
__global__ __launch_bounds__(256) void gate_kernel(
    const float* __restrict__ x, const float* __restrict__ Wg,
    const float* __restrict__ bg, int* __restrict__ tok_e,
    float* __restrict__ tok_w, int* __restrict__ counts,
    unsigned short* __restrict__ xb) {
  const int wave = threadIdx.x >> 6;
  const int lane = threadIdx.x & 63;
  const int t = blockIdx.x * 4 + wave;
  const float* xr = x + (size_t)t * 1024;
  unsigned short* xrow = xb + (size_t)t * 1024;
  double acc[8] = {0, 0, 0, 0, 0, 0, 0, 0};
  for (int i = 0; i < 16; ++i) {
    const int d = i * 64 + lane;
    const float vx = xr[d];
    xrow[d] = f2bf(vx);
    const double xv = (double)vx;
    const float* wr = Wg + d * 8;
#pragma unroll
    for (int e = 0; e < 8; ++e) acc[e] += xv * (double)wr[e];
  }
#pragma unroll
  for (int e = 0; e < 8; ++e) {
    double v = acc[e];
#pragma unroll
    for (int off = 32; off > 0; off >>= 1) v += __shfl_xor(v, off, 64);
    acc[e] = v + (double)bg[e];
  }
  if (lane == 0) {
    int e0 = 0;
#pragma unroll
    for (int e = 1; e < 8; ++e)
      if (acc[e] > acc[e0]) e0 = e;
    int e1 = (e0 == 0) ? 1 : 0;
#pragma unroll
    for (int e = 0; e < 8; ++e) {
      if (e != e0 && acc[e] > acc[e1]) e1 = e;
    }
    const double m = acc[e0];
    double s = 0.0;
#pragma unroll
    for (int e = 0; e < 8; ++e) s += exp(acc[e] - m);
    const double p0 = exp(acc[e0] - m) / s;
    const double p1 = exp(acc[e1] - m) / s;
    const double den = p0 + p1 + 1e-9;
    tok_e[2 * t] = e0;
    tok_e[2 * t + 1] = e1;
    tok_w[2 * t] = (float)(p0 / den);
    tok_w[2 * t + 1] = (float)(p1 / den);
    atomicAdd(&counts[e0], 1);
    atomicAdd(&counts[e1], 1);
  }
}

// ---------------- scan + scatter fused (single block) ----------------
__global__ __launch_bounds__(256) void scan_scatter_kernel(
    const int* __restrict__ counts, const int* __restrict__ tok_e,
    int* __restrict__ offsets, int* __restrict__ pair_token,
    int* __restrict__ tok_slot) {
  __shared__ int scur[8];
  const int tid = threadIdx.x;
  if (tid == 0) {
    int s = 0;
    for (int e = 0; e < 8; ++e) {
      offsets[e] = s;
      scur[e] = s;
      s += counts[e];
    }
  }
  __syncthreads();
  for (int t = tid; t < 4096; t += 256) {
#pragma unroll
    for (int j = 0; j < 2; ++j) {
      const int e = tok_e[2 * t + j];
      const int slot = atomicAdd(&scur[e], 1);
      pair_token[slot] = t;
      tok_slot[2 * t + j] = slot;
    }
  }
}

// -------- W1[e][k][f] -> W1t[e][f-f0][k] (bf16), LDS-tiled ----------------
__global__ __launch_bounds__(256) void transW1_kernel(
    const float* __restrict__ W1, unsigned short* __restrict__ W1t, int FC,
    int f0) {
  const int e = blockIdx.z;
  const int fb = blockIdx.x * 32;
  const int kb = blockIdx.y * 512;
  __shared__ __align__(16) unsigned short T[32][520];

  const int tid = threadIdx.x;
  const int fo = tid & 31;
  const int kg = tid >> 5;
  const float* src =
      W1 + ((size_t)e * 1024 + kb + kg * 64) * 4096 + f0 + fb + fo;
#pragma unroll
  for (int i8 = 0; i8 < 8; ++i8) {
    uint4 pk;
    const float* s8 = src + (size_t)i8 * 8 * 4096;
    pk.x = (unsigned)f2bf(s8[0]) | ((unsigned)f2bf(s8[(size_t)4096]) << 16);
    pk.y = (unsigned)f2bf(s8[(size_t)2 * 4096]) |
           ((unsigned)f2bf(s8[(size_t)3 * 4096]) << 16);
    pk.z = (unsigned)f2bf(s8[(size_t)4 * 4096]) |
           ((unsigned)f2bf(s8[(size_t)5 * 4096]) << 16);
    pk.w = (unsigned)f2bf(s8[(size_t)6 * 4096]) |
           ((unsigned)f2bf(s8[(size_t)7 * 4096]) << 16);
    *(uint4*)&T[fo][kg * 64 + i8 * 8] = pk;
  }
  __syncthreads();
  const int fr = tid >> 3;
  const int sg = tid & 7;
  unsigned short* dst = W1t + ((size_t)e * FC + fb + fr) * 1024 + kb;
#pragma unroll
  for (int j = 0; j < 8; ++j) {
    const int c = sg + j * 8;
    *(uint4*)(dst + c * 8) = *(const uint4*)&T[fr][c * 8];
  }
}

// -------- W2[e][f][d] -> W2t[e][d][f-f0] (bf16), LDS-tiled ----------------
__global__ __launch_bounds__(256) void transW2_kernel(
    const float* __restrict__ W2, unsigned short* __restrict__ W2t, int FC,
    int f0) {
  const int e = blockIdx.z;
  const int db = blockIdx.x * 32;
  const int fb = blockIdx.y * 256;
  __shared__ __align__(16) unsigned short T[32][264];

  const int tid = threadIdx.x;
  const int dd = tid & 31;
  const int fg = tid >> 5;
  const float* src =
      W2 + ((size_t)e * 4096 + f0 + fb + fg * 32) * 1024 + db + dd;
#pragma unroll
  for (int i8 = 0; i8 < 4; ++i8) {
    uint4 pk;
    const float* s8 = src + (size_t)i8 * 8 * 1024;
    pk.x = (unsigned)f2bf(s8[0]) | ((unsigned)f2bf(s8[1024]) << 16);
    pk.y = (unsigned)f2bf(s8[2048]) | ((unsigned)f2bf(s8[3072]) << 16);
    pk.z = (unsigned)f2bf(s8[4096]) | ((unsigned)f2bf(s8[5120]) << 16);
    pk.w = (unsigned)f2bf(s8[6144]) | ((unsigned)f2bf(s8[7168]) << 16);
    *(uint4*)&T[dd][fg * 32 + i8 * 8] = pk;
  }
  __syncthreads();
  const int dr = tid >> 3;
  const int sg = tid & 7;
  unsigned short* dst = W2t + ((size_t)e * 1024 + db + dr) * FC + fb;
#pragma unroll
  for (int j = 0; j < 4; ++j) {
    const int c = sg + j * 8;
    *(uint4*)(dst + c * 8) = *(const uint4*)&T[dr][c * 8];
  }
}

// Interleaved ds_read / MFMA compute body (counted lgkmcnt; DS in-order).
#define COMPUTE_BODY(ALDS, BLDS)                                          \
  {                                                                       \
    bf16x8 af[4], bfr[4];                                                 \
    af[0] = ldsr128(&ALDS[rdA[0]]);                                       \
    bfr[0] = ldsr128(&BLDS[rdB[0]]);                                      \
    af[1] = ldsr128(&ALDS[rdA[1]]);                                       \
    bfr[1] = ldsr128(&BLDS[rdB[1]]);                                      \
    af[2] = ldsr128(&ALDS[rdA[2]]);                                       \
    bfr[2] = ldsr128(&BLDS[rdB[2]]);                                      \
    af[3] = ldsr128(&ALDS[rdA[3]]);                                       \
    bfr[3] = ldsr128(&BLDS[rdB[3]]);                                      \
    asm volatile("s_waitcnt lgkmcnt(6)" ::: "memory");                    \
    __builtin_amdgcn_sched_barrier(0);                                    \
    acc[0][0] = MFMA16(af[0], bfr[0], acc[0][0]);                         \
    __builtin_amdgcn_sched_barrier(0);                                    \
    asm volatile("s_waitcnt lgkmcnt(4)" ::: "memory");                    \
    __builtin_amdgcn_sched_barrier(0);                                    \
    acc[0][1] = MFMA16(af[0], bfr[1], acc[0][1]);                         \
    acc[1][0] = MFMA16(af[1], bfr[0], acc[1][0]);                         \
    acc[1][1] = MFMA16(af[1], bfr[1], acc[1][1]);                         \
    __builtin_amdgcn_sched_barrier(0);                                    \
    asm volatile("s_waitcnt lgkmcnt(2)" ::: "memory");                    \
    __builtin_amdgcn_sched_barrier(0);                                    \
    acc[0][2] = MFMA16(af[0], bfr[2], acc[0][2]);                         \
    acc[1][2] = MFMA16(af[1], bfr[2], acc[1][2]);                         \
    acc[2][0] = MFMA16(af[2], bfr[0], acc[2][0]);                         \
    acc[2][1] = MFMA16(af[2], bfr[1], acc[2][1]);                         \
    acc[2][2] = MFMA16(af[2], bfr[2], acc[2][2]);                         \
    __builtin_amdgcn_sched_barrier(0);                                    \
    asm volatile("s_waitcnt lgkmcnt(0)" ::: "memory");                    \
    __builtin_amdgcn_sched_barrier(0);                                    \
    acc[0][3] = MFMA16(af[0], bfr[3], acc[0][3]);                         \
    acc[1][3] = MFMA16(af[1], bfr[3], acc[1][3]);                         \
    acc[2][3] = MFMA16(af[2], bfr[3], acc[2][3]);                         \
    acc[3][0] = MFMA16(af[3], bfr[0], acc[3][0]);                         \
    acc[3][1] = MFMA16(af[3], bfr[1], acc[3][1]);                         \
    acc[3][2] = MFMA16(af[3], bfr[2], acc[3][2]);                         \
    acc[3][3] = MFMA16(af[3], bfr[3], acc[3][3]);                         \
    __builtin_amdgcn_sched_barrier(0);                                    \
  }

// ---------------- GEMM1: H[slot][n] = relu(xb[tok] @ W1t[e] + b1) -----------
// 128x128 tile, BK=32, 4 waves 2x2, gload_lds + XOR swizzle, 2-buf counted.
// m-fastest tile order: consecutive blocks share the B panel (L2 reuse).
__global__ __launch_bounds__(256) void gemm1_kernel(
    const unsigned short* __restrict__ xb,
    const unsigned short* __restrict__ W1t, const float* __restrict__ b1,
    const int* __restrict__ counts, const int* __restrict__ offsets,
    const int* __restrict__ pair_token, unsigned short* __restrict__ H, int FC,
    int f0) {
  const int bid = blockIdx.x;
  const int e = bid & 7;  // XCD pinning
  const int lid = bid >> 3;
  const int m0 = (lid & 31) * 128;  // m fastest
  const int n0 = (lid >> 5) * 128;
  const int count = counts[e];
  if (m0 >= count) return;
  const int offset = offsets[e];

  __shared__ __align__(16) unsigned short Alds[2][128 * 32];
  __shared__ __align__(16) unsigned short Blds[2][128 * 32];
  __shared__ int toklds[128];

  const int tid = threadIdx.x;
  if (tid < 128) {
    int r = m0 + tid;
    if (r >= count) r = count - 1;
    toklds[tid] = pair_token[offset + r];
  }
  __syncthreads();

  const int lane = tid & 63;
  const int wave = tid >> 6;
  const int srow = lane >> 2;
  const int kc = lane & 3;
  const unsigned short* aga[2];
  const unsigned short* bga[2];
  int ldso[2];
#pragma unroll
  for (int i = 0; i < 2; ++i) {
    const int ar = wave * 32 + i * 16 + srow;
    const int xr = (ar >> 1) & 3;  // source-chunk XOR swizzle
    aga[i] = xb + (size_t)toklds[ar] * 1024 + (kc ^ xr) * 8;
    bga[i] = W1t + ((size_t)e * FC + n0 + ar) * 1024 + (kc ^ xr) * 8;
    ldso[i] = (wave * 32 + i * 16) * 32;
  }

  const int wm = (wave >> 1) * 64;
  const int wn = (wave & 1) * 64;
  const int l16 = lane & 15;
  const int lk = lane >> 4;
  int rdA[4], rdB[4];
#pragma unroll
  for (int mi = 0; mi < 4; ++mi) {
    const int row = wm + mi * 16 + l16;
    rdA[mi] = row * 32 + ((lk ^ ((row >> 1) & 3)) << 3);
  }
#pragma unroll
  for (int nj = 0; nj < 4; ++nj) {
    const int f = wn + nj * 16 + l16;
    rdB[nj] = f * 32 + ((lk ^ ((f >> 1) & 3)) << 3);
  }

  f32x4 acc[4][4] = {};

  auto STAGE = [&](int kt, int buf) {
#pragma unroll
    for (int i = 0; i < 2; ++i) {
      gload_lds16(aga[i] + kt, &Alds[buf][ldso[i]]);
      gload_lds16(bga[i] + kt, &Blds[buf][ldso[i]]);
    }
  };

  const int NTk = 32;  // K = 1024
  STAGE(0, 0);
  for (int t = 0; t < NTk; ++t) {
    __builtin_amdgcn_s_barrier();  // all waves done reading buf[(t+1)&1]
    if (t + 1 < NTk) {
      STAGE((t + 1) * 32, (t + 1) & 1);
      asm volatile("s_waitcnt vmcnt(4)" ::: "memory");  // t's loads landed
    } else {
      asm volatile("s_waitcnt vmcnt(0)" ::: "memory");
    }
    __builtin_amdgcn_s_barrier();  // buf[t&1] staged by all waves
    __builtin_amdgcn_sched_barrier(0);
    COMPUTE_BODY(Alds[t & 1], Blds[t & 1]);
  }

#pragma unroll
  for (int mi = 0; mi < 4; ++mi) {
#pragma unroll
    for (int r = 0; r < 4; ++r) {
      const int rl = m0 + wm + mi * 16 + lk * 4 + r;
      if (rl >= count) continue;
      unsigned short* hrow = H + (size_t)(offset + rl) * FC;
#pragma unroll
      for (int nj = 0; nj < 4; ++nj) {
        const int c = n0 + wn + nj * 16 + l16;
        float v = acc[mi][nj][r] + b1[e * 4096 + f0 + c];
        hrow[c] = f2bf(v > 0.f ? v : 0.f);
      }
    }
  }
}

// ------- GEMM2: P[slot][d] (bf16) (+)= H[slot] @ W2t[e] (+ b2) --------------
__global__ __launch_bounds__(256) void gemm2_kernel(
    const unsigned short* __restrict__ H,
    const unsigned short* __restrict__ W2t, const float* __restrict__ b2,
    const int* __restrict__ counts, const int* __restrict__ offsets,
    unsigned short* __restrict__ P, int FC, int firstChunk) {
  const int bid = blockIdx.x;
  const int e = bid & 7;  // XCD pinning
  const int lid = bid >> 3;
  const int m0 = (lid & 31) * 128;  // m fastest
  const int n0 = (lid >> 5) * 128;  // 8 n-tiles (N=1024)
  const int count = counts[e];
  if (m0 >= count) return;
  const int offset = offsets[e];

  __shared__ __align__(16) unsigned short Alds[2][128 * 32];
  __shared__ __align__(16) unsigned short Blds[2][128 * 32];

  const int tid = threadIdx.x;
  const int lane = tid & 63;
  const int wave = tid >> 6;
  const int srow = lane >> 2;
  const int kc = lane & 3;
  const unsigned short* aga[2];
  const unsigned short* bga[2];
  int ldso[2];
#pragma unroll
  for (int i = 0; i < 2; ++i) {
    const int tr = wave * 32 + i * 16 + srow;
    int ar = m0 + tr;
    if (ar >= count) ar = count - 1;
    const int xr = (tr >> 1) & 3;
    aga[i] = H + (size_t)(offset + ar) * FC + (kc ^ xr) * 8;
    bga[i] = W2t + ((size_t)e * 1024 + n0 + tr) * FC + (kc ^ xr) * 8;
    ldso[i] = (wave * 32 + i * 16) * 32;
  }

  const int wm = (wave >> 1) * 64;
  const int wn = (wave & 1) * 64;
  const int l16 = lane & 15;
  const int lk = lane >> 4;
  int rdA[4], rdB[4];
#pragma unroll
  for (int mi = 0; mi < 4; ++mi) {
    const int row = wm + mi * 16 + l16;
    rdA[mi] = row * 32 + ((lk ^ ((row >> 1) & 3)) << 3);
  }
#pragma unroll
  for (int nj = 0; nj < 4; ++nj) {
    const int f = wn + nj * 16 + l16;
    rdB[nj] = f * 32 + ((lk ^ ((f >> 1) & 3)) << 3);
  }

  f32x4 acc[4][4] = {};

  auto STAGE = [&](int kt, int buf) {
#pragma unroll
    for (int i = 0; i < 2; ++i) {
      gload_lds16(aga[i] + kt, &Alds[buf][ldso[i]]);
      gload_lds16(bga[i] + kt, &Blds[buf][ldso[i]]);
    }
  };

  const int NTk = FC / 32;
  STAGE(0, 0);
  for (int t = 0; t < NTk; ++t) {
    __builtin_amdgcn_s_barrier();
    if (t + 1 < NTk) {
      STAGE((t + 1) * 32, (t + 1) & 1);
      asm volatile("s_waitcnt vmcnt(4)" ::: "memory");
    } else {
      asm volatile("s_waitcnt vmcnt(0)" ::: "memory");
    }
    __builtin_amdgcn_s_barrier();
    __builtin_amdgcn_sched_barrier(0);
    COMPUTE_BODY(Alds[t & 1], Blds[t & 1]);
  }

#pragma unroll
  for (int mi = 0; mi < 4; ++mi) {
#pragma unroll
    for (int r = 0; r < 4; ++r) {
      const int rl = m0 + wm + mi * 16 + lk * 4 + r;
      if (rl >= count) continue;
      unsigned short* prow = P + (size_t)(offset + rl) * 1024;
#pragma unroll
      for (int nj = 0; nj < 4; ++nj) {
        const int c = n0 + wn + nj * 16 + l16;
        float v = acc[mi][nj][r];
        if (firstChunk) {
          prow[c] = f2bf(v + b2[e * 1024 + c]);
        } else {
          prow[c] = f2bf(bf2f(prow[c]) + v);
        }
      }
    }
  }
}

// ---------------- combine: out[t] = w0*P[s0] + w1*P[s1] (bf16 P) ------------
__global__ __launch_bounds__(256) void combine_kernel(
    const unsigned short* __restrict__ P, const int* __restrict__ tok_slot,
    const float* __restrict__ tok_w, float* __restrict__ out) {
  const int t = blockIdx.x;
  const int d = threadIdx.x * 4;
  const int s0 = tok_slot[2 * t];
  const int s1 = tok_slot[2 * t + 1];
  const float w0 = tok_w[2 * t];
  const float w1 = tok_w[2 * t + 1];
  const ushort4 a = *(const ushort4*)&P[(size_t)s0 * 1024 + d];
  const ushort4 b = *(const ushort4*)&P[(size_t)s1 * 1024 + d];
  float4 r;
  r.x = w0 * bf2f(a.x) + w1 * bf2f(b.x);
  r.y = w0 * bf2f(a.y) + w1 * bf2f(b.y);
  r.z = w0 * bf2f(a.z) + w1 * bf2f(b.z);
  r.w = w0 * bf2f(a.w) + w1 * bf2f(b.w);
  *(float4*)&out[(size_t)t * 1024 + d] = r;
}

extern "C" void kernel_launch(void* const* d_in, const int* in_sizes, int n_in,
                              void* d_out, int out_size, void* d_ws,
                              size_t ws_size, hipStream_t stream) {
  const float* x = (const float*)d_in[0];
  const float* Wg = (const float*)d_in[1];
  const float* bg = (const float*)d_in[2];
  const float* W1 = (const float*)d_in[3];
  const float* b1 = (const float*)d_in[4];
  const float* W2 = (const float*)d_in[5];
  const float* b2 = (const float*)d_in[6];
  float* out = (float*)d_out;

  char* w = (char*)d_ws;
  int* counts = (int*)w;
  int* offsets = counts + 16;
  int* tok_e = (int*)(w + 1024);
  float* tok_w = (float*)(w + 1024 + 32768);
  int* pair_token = (int*)(w + 1024 + 65536);
  int* tok_slot = (int*)(w + 1024 + 98304);
  unsigned short* xb = (unsigned short*)(w + 256 * 1024);        // 8MB
  unsigned short* P = (unsigned short*)(w + 256 * 1024 + 8 * 1024 * 1024);  // 16MB bf16
  char* big = w + 256 * 1024 + 8 * 1024 * 1024 + 16 * 1024 * 1024;
  const size_t avail =
      ws_size - (256 * 1024 + 8 * 1024 * 1024 + 16 * 1024 * 1024);

  // per-chunk: W1t 16384*FC + W2t 16384*FC + H 16384*FC bytes
  int FC = 4096;
  while (FC > 256 && (size_t)FC * 49152 > avail) FC >>= 1;

  unsigned short* W1t = (unsigned short*)big;
  unsigned short* W2t = W1t + (size_t)8 * FC * 1024;
  unsigned short* Hc = W2t + (size_t)8 * 1024 * FC;

  (void)hipMemsetAsync(counts, 0, 64, stream);

  gate_kernel<<<1024, 256, 0, stream>>>(x, Wg, bg, tok_e, tok_w, counts, xb);
  scan_scatter_kernel<<<1, 256, 0, stream>>>(counts, tok_e, offsets,
                                             pair_token, tok_slot);

  const int NT = FC / 128;
  for (int f0 = 0; f0 < 4096; f0 += FC) {
    transW1_kernel<<<dim3(FC / 32, 2, 8), 256, 0, stream>>>(W1, W1t, FC, f0);
    transW2_kernel<<<dim3(32, FC / 256, 8), 256, 0, stream>>>(W2, W2t, FC, f0);
    gemm1_kernel<<<8 * 32 * NT, 256, 0, stream>>>(
        xb, W1t, b1, counts, offsets, pair_token, Hc, FC, f0);
    gemm2_kernel<<<8 * 32 * 8, 256, 0, stream>>>(
        Hc, W2t, b2, counts, offsets, P, FC, f0 == 0 ? 1 : 0);
  }
  combine_kernel<<<4096, 256, 0, stream>>>(P, tok_slot, tok_w, out);
}

// Round 13
// 422.424 us; speedup vs baseline: 1.1278x; 1.0756x over previous
//
#include <hip/hip_runtime.h>
#include <hip/hip_bf16.h>

// SimpleMoE: B=2,S=2048 -> 4096 tokens, DIM=1024, FF=4096, E=8, top-2 routing.
// Round 13: best-measured assembly = r10 GEMM cores verbatim (n-fastest,
// split-K=2 gemm2, counted vmcnt/lgkm, XOR swizzle, XCD pinning) + r12's
// bf16 partial buffers (both splits) + LDS-tiled transposes + fused gate.

typedef __attribute__((ext_vector_type(8))) short bf16x8;
typedef __attribute__((ext_vector_type(4))) float f32x4;

#define MFMA16(a, b, c) __builtin_amdgcn_mfma_f32_16x16x32_bf16((a), (b), (c), 0, 0, 0)

__device__ __forceinline__ unsigned short f2bf(float f) {
  unsigned u = __builtin_bit_cast(unsigned, f);
  u += 0x7FFFu + ((u >> 16) & 1u);
  return (unsigned short)(u >> 16);
}

__device__ __forceinline__ float bf2f(unsigned short s) {
  return __builtin_bit_cast(float, (unsigned)s << 16);
}

__device__ __forceinline__ void gload_lds16(const void* g, void* l) {
  __builtin_amdgcn_global_load_lds(
      (const __attribute__((address_space(1))) unsigned int*)g,
      (__attribute__((address_space(3))) unsigned int*)l, 16, 0, 0);
}

// inline-asm LDS read: keeps the compiler from serializing ds_read behind
// in-flight global_load_lds (false alias) with a vmcnt(0).
__device__ __forceinline__ bf16x8 ldsr128(const void* p) {
  bf16x8 r;
  unsigned a = (unsigned)(unsigned long long)p;
  asm volatile("ds_read_b128 %0, %1" : "=v"(r) : "v"(a));
  return r;
}

// ---------------- gate: logits (fp64), softmax, top-2, counts; also x->bf16 --
__global__ __launch_bounds__(256) void gate_kernel(
    const float* __restrict__ x, const float* __restrict__ Wg,
    const float* __restrict__ bg, int* __restrict__ tok_e,
    float* __restrict__ tok_w, int* __restrict__ counts,
    unsigned short* __restrict__ xb) {
  const int wave = threadIdx.x >> 6;
  const int lane = threadIdx.x & 63;
  const int t = blockIdx.x * 4 + wave;
  const float* xr = x + (size_t)t * 1024;
  unsigned short* xrow = xb + (size_t)t * 1024;
  double acc[8] = {0, 0, 0, 0, 0, 0, 0, 0};
  for (int i = 0; i < 16; ++i) {
    const int d = i * 64 + lane;
    const float vx = xr[d];
    xrow[d] = f2bf(vx);
    const double xv = (double)vx;
    const float* wr = Wg + d * 8;
#pragma unroll
    for (int e = 0; e < 8; ++e) acc[e] += xv * (double)wr[e];
  }
#pragma unroll
  for (int e = 0; e < 8; ++e) {
    double v = acc[e];
#pragma unroll
    for (int off = 32; off > 0; off >>= 1) v += __shfl_xor(v, off, 64);
    acc[e] = v + (double)bg[e];
  }
  if (lane == 0) {
    int e0 = 0;
#pragma unroll
    for (int e = 1; e < 8; ++e)
      if (acc[e] > acc[e0]) e0 = e;
    int e1 = (e0 == 0) ? 1 : 0;
#pragma unroll
    for (int e = 0; e < 8; ++e) {
      if (e != e0 && acc[e] > acc[e1]) e1 = e;
    }
    const double m = acc[e0];
    double s = 0.0;
#pragma unroll
    for (int e = 0; e < 8; ++e) s += exp(acc[e] - m);
    const double p0 = exp(acc[e0] - m) / s;
    const double p1 = exp(acc[e1] - m) / s;
    const double den = p0 + p1 + 1e-9;
    tok_e[2 * t] = e0;
    tok_e[2 * t + 1] = e1;
    tok_w[2 * t] = (float)(p0 / den);
    tok_w[2 * t + 1] = (float)(p1 / den);
    atomicAdd(&counts[e0], 1);
    atomicAdd(&counts[e1], 1);
  }
}

// ---------------- scan + scatter fused (single block) ----------------
__global__ __launch_bounds__(256) void scan_scatter_kernel(
    const int* __restrict__ counts, const int* __restrict__ tok_e,
    int* __restrict__ offsets, int* __restrict__ pair_token,
    int* __restrict__ tok_slot) {
  __shared__ int scur[8];
  const int tid = threadIdx.x;
  if (tid == 0) {
    int s = 0;
    for (int e = 0; e < 8; ++e) {
      offsets[e] = s;
      scur[e] = s;
      s += counts[e];
    }
  }
  __syncthreads();
  for (int t = tid; t < 4096; t += 256) {
#pragma unroll
    for (int j = 0; j < 2; ++j) {
      const int e = tok_e[2 * t + j];
      const int slot = atomicAdd(&scur[e], 1);
      pair_token[slot] = t;
      tok_slot[2 * t + j] = slot;
    }
  }
}

// -------- W1[e][k][f] -> W1t[e][f-f0][k] (bf16), LDS-tiled ----------------
__global__ __launch_bounds__(256) void transW1_kernel(
    const float* __restrict__ W1, unsigned short* __restrict__ W1t, int FC,
    int f0) {
  const int e = blockIdx.z;
  const int fb = blockIdx.x * 32;
  const int kb = blockIdx.y * 512;
  __shared__ __align__(16) unsigned short T[32][520];

  const int tid = threadIdx.x;
  const int fo = tid & 31;
  const int kg = tid >> 5;
  const float* src =
      W1 + ((size_t)e * 1024 + kb + kg * 64) * 4096 + f0 + fb + fo;
#pragma unroll
  for (int i8 = 0; i8 < 8; ++i8) {
    uint4 pk;
    const float* s8 = src + (size_t)i8 * 8 * 4096;
    pk.x = (unsigned)f2bf(s8[0]) | ((unsigned)f2bf(s8[(size_t)4096]) << 16);
    pk.y = (unsigned)f2bf(s8[(size_t)2 * 4096]) |
           ((unsigned)f2bf(s8[(size_t)3 * 4096]) << 16);
    pk.z = (unsigned)f2bf(s8[(size_t)4 * 4096]) |
           ((unsigned)f2bf(s8[(size_t)5 * 4096]) << 16);
    pk.w = (unsigned)f2bf(s8[(size_t)6 * 4096]) |
           ((unsigned)f2bf(s8[(size_t)7 * 4096]) << 16);
    *(uint4*)&T[fo][kg * 64 + i8 * 8] = pk;
  }
  __syncthreads();
  const int fr = tid >> 3;
  const int sg = tid & 7;
  unsigned short* dst = W1t + ((size_t)e * FC + fb + fr) * 1024 + kb;
#pragma unroll
  for (int j = 0; j < 8; ++j) {
    const int c = sg + j * 8;
    *(uint4*)(dst + c * 8) = *(const uint4*)&T[fr][c * 8];
  }
}

// -------- W2[e][f][d] -> W2t[e][d][f-f0] (bf16), LDS-tiled ----------------
__global__ __launch_bounds__(256) void transW2_kernel(
    const float* __restrict__ W2, unsigned short* __restrict__ W2t, int FC,
    int f0) {
  const int e = blockIdx.z;
  const int db = blockIdx.x * 32;
  const int fb = blockIdx.y * 256;
  __shared__ __align__(16) unsigned short T[32][264];

  const int tid = threadIdx.x;
  const int dd = tid & 31;
  const int fg = tid >> 5;
  const float* src =
      W2 + ((size_t)e * 4096 + f0 + fb + fg * 32) * 1024 + db + dd;
#pragma unroll
  for (int i8 = 0; i8 < 4; ++i8) {
    uint4 pk;
    const float* s8 = src + (size_t)i8 * 8 * 1024;
    pk.x = (unsigned)f2bf(s8[0]) | ((unsigned)f2bf(s8[1024]) << 16);
    pk.y = (unsigned)f2bf(s8[2048]) | ((unsigned)f2bf(s8[3072]) << 16);
    pk.z = (unsigned)f2bf(s8[4096]) | ((unsigned)f2bf(s8[5120]) << 16);
    pk.w = (unsigned)f2bf(s8[6144]) | ((unsigned)f2bf(s8[7168]) << 16);
    *(uint4*)&T[dd][fg * 32 + i8 * 8] = pk;
  }
  __syncthreads();
  const int dr = tid >> 3;
  const int sg = tid & 7;
  unsigned short* dst = W2t + ((size_t)e * 1024 + db + dr) * FC + fb;
#pragma unroll
  for (int j = 0; j < 4; ++j) {
    const int c = sg + j * 8;
    *(uint4*)(dst + c * 8) = *(const uint4*)&T[dr][c * 8];
  }
}

// Interleaved ds_read / MFMA compute body (counted lgkmcnt; DS in-order).
#define COMPUTE_BODY(ALDS, BLDS)                                          \
  {                                                                       \
    bf16x8 af[4], bfr[4];                                                 \
    af[0] = ldsr128(&ALDS[rdA[0]]);                                       \
    bfr[0] = ldsr128(&BLDS[rdB[0]]);                                      \
    af[1] = ldsr128(&ALDS[rdA[1]]);                                       \
    bfr[1] = ldsr128(&BLDS[rdB[1]]);                                      \
    af[2] = ldsr128(&ALDS[rdA[2]]);                                       \
    bfr[2] = ldsr128(&BLDS[rdB[2]]);                                      \
    af[3] = ldsr128(&ALDS[rdA[3]]);                                       \
    bfr[3] = ldsr128(&BLDS[rdB[3]]);                                      \
    asm volatile("s_waitcnt lgkmcnt(6)" ::: "memory");                    \
    __builtin_amdgcn_sched_barrier(0);                                    \
    acc[0][0] = MFMA16(af[0], bfr[0], acc[0][0]);                         \
    __builtin_amdgcn_sched_barrier(0);                                    \
    asm volatile("s_waitcnt lgkmcnt(4)" ::: "memory");                    \
    __builtin_amdgcn_sched_barrier(0);                                    \
    acc[0][1] = MFMA16(af[0], bfr[1], acc[0][1]);                         \
    acc[1][0] = MFMA16(af[1], bfr[0], acc[1][0]);                         \
    acc[1][1] = MFMA16(af[1], bfr[1], acc[1][1]);                         \
    __builtin_amdgcn_sched_barrier(0);                                    \
    asm volatile("s_waitcnt lgkmcnt(2)" ::: "memory");                    \
    __builtin_amdgcn_sched_barrier(0);                                    \
    acc[0][2] = MFMA16(af[0], bfr[2], acc[0][2]);                         \
    acc[1][2] = MFMA16(af[1], bfr[2], acc[1][2]);                         \
    acc[2][0] = MFMA16(af[2], bfr[0], acc[2][0]);                         \
    acc[2][1] = MFMA16(af[2], bfr[1], acc[2][1]);                         \
    acc[2][2] = MFMA16(af[2], bfr[2], acc[2][2]);                         \
    __builtin_amdgcn_sched_barrier(0);                                    \
    asm volatile("s_waitcnt lgkmcnt(0)" ::: "memory");                    \
    __builtin_amdgcn_sched_barrier(0);                                    \
    acc[0][3] = MFMA16(af[0], bfr[3], acc[0][3]);                         \
    acc[1][3] = MFMA16(af[1], bfr[3], acc[1][3]);                         \
    acc[2][3] = MFMA16(af[2], bfr[3], acc[2][3]);                         \
    acc[3][0] = MFMA16(af[3], bfr[0], acc[3][0]);                         \
    acc[3][1] = MFMA16(af[3], bfr[1], acc[3][1]);                         \
    acc[3][2] = MFMA16(af[3], bfr[2], acc[3][2]);                         \
    acc[3][3] = MFMA16(af[3], bfr[3], acc[3][3]);                         \
    __builtin_amdgcn_sched_barrier(0);                                    \
  }

// ---------------- GEMM1: H[slot][n] = relu(xb[tok] @ W1t[e] + b1) -----------
// 128x128 tile, BK=32, 4 waves 2x2, gload_lds + XOR swizzle, 2-buf counted.
// n-fastest tile order (r10): A panel reused by consecutive blocks.
__global__ __launch_bounds__(256) void gemm1_kernel(
    const unsigned short* __restrict__ xb,
    const unsigned short* __restrict__ W1t, const float* __restrict__ b1,
    const int* __restrict__ counts, const int* __restrict__ offsets,
    const int* __restrict__ pair_token, unsigned short* __restrict__ H, int FC,
    int f0, int NT) {
  const int bid = blockIdx.x;
  const int e = bid & 7;  // XCD pinning
  const int lid = bid >> 3;
  const int n0 = (lid % NT) * 128;
  const int m0 = (lid / NT) * 128;
  const int count = counts[e];
  if (m0 >= count) return;
  const int offset = offsets[e];

  __shared__ __align__(16) unsigned short Alds[2][128 * 32];
  __shared__ __align__(16) unsigned short Blds[2][128 * 32];
  __shared__ int toklds[128];

  const int tid = threadIdx.x;
  if (tid < 128) {
    int r = m0 + tid;
    if (r >= count) r = count - 1;
    toklds[tid] = pair_token[offset + r];
  }
  __syncthreads();

  const int lane = tid & 63;
  const int wave = tid >> 6;
  const int srow = lane >> 2;
  const int kc = lane & 3;
  const unsigned short* aga[2];
  const unsigned short* bga[2];
  int ldso[2];
#pragma unroll
  for (int i = 0; i < 2; ++i) {
    const int ar = wave * 32 + i * 16 + srow;
    const int xr = (ar >> 1) & 3;  // source-chunk XOR swizzle
    aga[i] = xb + (size_t)toklds[ar] * 1024 + (kc ^ xr) * 8;
    bga[i] = W1t + ((size_t)e * FC + n0 + ar) * 1024 + (kc ^ xr) * 8;
    ldso[i] = (wave * 32 + i * 16) * 32;
  }

  const int wm = (wave >> 1) * 64;
  const int wn = (wave & 1) * 64;
  const int l16 = lane & 15;
  const int lk = lane >> 4;
  int rdA[4], rdB[4];
#pragma unroll
  for (int mi = 0; mi < 4; ++mi) {
    const int row = wm + mi * 16 + l16;
    rdA[mi] = row * 32 + ((lk ^ ((row >> 1) & 3)) << 3);
  }
#pragma unroll
  for (int nj = 0; nj < 4; ++nj) {
    const int f = wn + nj * 16 + l16;
    rdB[nj] = f * 32 + ((lk ^ ((f >> 1) & 3)) << 3);
  }

  f32x4 acc[4][4] = {};

  auto STAGE = [&](int kt, int buf) {
#pragma unroll
    for (int i = 0; i < 2; ++i) {
      gload_lds16(aga[i] + kt, &Alds[buf][ldso[i]]);
      gload_lds16(bga[i] + kt, &Blds[buf][ldso[i]]);
    }
  };

  const int NTk = 32;  // K = 1024
  STAGE(0, 0);
  for (int t = 0; t < NTk; ++t) {
    __builtin_amdgcn_s_barrier();  // all waves done reading buf[(t+1)&1]
    if (t + 1 < NTk) {
      STAGE((t + 1) * 32, (t + 1) & 1);
      asm volatile("s_waitcnt vmcnt(4)" ::: "memory");  // t's loads landed
    } else {
      asm volatile("s_waitcnt vmcnt(0)" ::: "memory");
    }
    __builtin_amdgcn_s_barrier();  // buf[t&1] staged by all waves
    __builtin_amdgcn_sched_barrier(0);
    COMPUTE_BODY(Alds[t & 1], Blds[t & 1]);
  }

#pragma unroll
  for (int mi = 0; mi < 4; ++mi) {
#pragma unroll
    for (int r = 0; r < 4; ++r) {
      const int rl = m0 + wm + mi * 16 + lk * 4 + r;
      if (rl >= count) continue;
      unsigned short* hrow = H + (size_t)(offset + rl) * FC;
#pragma unroll
      for (int nj = 0; nj < 4; ++nj) {
        const int c = n0 + wn + nj * 16 + l16;
        float v = acc[mi][nj][r] + b1[e * 4096 + f0 + c];
        hrow[c] = f2bf(v > 0.f ? v : 0.f);
      }
    }
  }
}

// ------- GEMM2: P[ks][slot][d] (bf16) = slice_ks(H[slot] @ W2t[e]) (+ b2) ---
// split-K=2, private bf16 partial buffers, n-fastest (r10 order).
__global__ __launch_bounds__(256) void gemm2_kernel(
    const unsigned short* __restrict__ H,
    const unsigned short* __restrict__ W2t, const float* __restrict__ b2,
    const int* __restrict__ counts, const int* __restrict__ offsets,
    unsigned short* __restrict__ P, int FC, int firstChunk) {
  const int bid = blockIdx.x;
  const int e = bid & 7;  // XCD pinning
  const int r2 = bid >> 3;
  const int n0 = (r2 & 7) * 128;          // 8 n-tiles (N=1024), fastest
  const int m0 = ((r2 >> 3) & 31) * 128;  // 32 m-tiles
  const int ks = r2 >> 8;                 // K split 0/1
  const int count = counts[e];
  if (m0 >= count) return;
  const int offset = offsets[e];
  const int KS = FC / 2;
  const int kb = ks * KS;
  unsigned short* Pb = P + (size_t)ks * 8192 * 1024;

  __shared__ __align__(16) unsigned short Alds[2][128 * 32];
  __shared__ __align__(16) unsigned short Blds[2][128 * 32];

  const int tid = threadIdx.x;
  const int lane = tid & 63;
  const int wave = tid >> 6;
  const int srow = lane >> 2;
  const int kc = lane & 3;
  const unsigned short* aga[2];
  const unsigned short* bga[2];
  int ldso[2];
#pragma unroll
  for (int i = 0; i < 2; ++i) {
    const int tr = wave * 32 + i * 16 + srow;
    int ar = m0 + tr;
    if (ar >= count) ar = count - 1;
    const int xr = (tr >> 1) & 3;
    aga[i] = H + (size_t)(offset + ar) * FC + kb + (kc ^ xr) * 8;
    bga[i] = W2t + ((size_t)e * 1024 + n0 + tr) * FC + kb + (kc ^ xr) * 8;
    ldso[i] = (wave * 32 + i * 16) * 32;
  }

  const int wm = (wave >> 1) * 64;
  const int wn = (wave & 1) * 64;
  const int l16 = lane & 15;
  const int lk = lane >> 4;
  int rdA[4], rdB[4];
#pragma unroll
  for (int mi = 0; mi < 4; ++mi) {
    const int row = wm + mi * 16 + l16;
    rdA[mi] = row * 32 + ((lk ^ ((row >> 1) & 3)) << 3);
  }
#pragma unroll
  for (int nj = 0; nj < 4; ++nj) {
    const int f = wn + nj * 16 + l16;
    rdB[nj] = f * 32 + ((lk ^ ((f >> 1) & 3)) << 3);
  }

  f32x4 acc[4][4] = {};

  auto STAGE = [&](int kt, int buf) {
#pragma unroll
    for (int i = 0; i < 2; ++i) {
      gload_lds16(aga[i] + kt, &Alds[buf][ldso[i]]);
      gload_lds16(bga[i] + kt, &Blds[buf][ldso[i]]);
    }
  };

  const int NTk = KS / 32;
  STAGE(0, 0);
  for (int t = 0; t < NTk; ++t) {
    __builtin_amdgcn_s_barrier();
    if (t + 1 < NTk) {
      STAGE((t + 1) * 32, (t + 1) & 1);
      asm volatile("s_waitcnt vmcnt(4)" ::: "memory");
    } else {
      asm volatile("s_waitcnt vmcnt(0)" ::: "memory");
    }
    __builtin_amdgcn_s_barrier();
    __builtin_amdgcn_sched_barrier(0);
    COMPUTE_BODY(Alds[t & 1], Blds[t & 1]);
  }

#pragma unroll
  for (int mi = 0; mi < 4; ++mi) {
#pragma unroll
    for (int r = 0; r < 4; ++r) {
      const int rl = m0 + wm + mi * 16 + lk * 4 + r;
      if (rl >= count) continue;
      unsigned short* prow = Pb + (size_t)(offset + rl) * 1024;
#pragma unroll
      for (int nj = 0; nj < 4; ++nj) {
        const int c = n0 + wn + nj * 16 + l16;
        float v = acc[mi][nj][r];
        if (ks == 0 && firstChunk) v += b2[e * 1024 + c];
        if (firstChunk) {
          prow[c] = f2bf(v);
        } else {
          prow[c] = f2bf(bf2f(prow[c]) + v);
        }
      }
    }
  }
}

// ---- combine: out[t] = w0*(P0[s0]+P1[s0]) + w1*(P0[s1]+P1[s1]) (bf16 P) ----
__global__ __launch_bounds__(256) void combine_kernel(
    const unsigned short* __restrict__ P, const int* __restrict__ tok_slot,
    const float* __restrict__ tok_w, float* __restrict__ out) {
  const int t = blockIdx.x;
  const int d = threadIdx.x * 4;
  const int s0 = tok_slot[2 * t];
  const int s1 = tok_slot[2 * t + 1];
  const float w0 = tok_w[2 * t];
  const float w1 = tok_w[2 * t + 1];
  const ushort4 a0 = *(const ushort4*)&P[(size_t)s0 * 1024 + d];
  const ushort4 a1 = *(const ushort4*)&P[(size_t)(8192 + s0) * 1024 + d];
  const ushort4 c0 = *(const ushort4*)&P[(size_t)s1 * 1024 + d];
  const ushort4 c1 = *(const ushort4*)&P[(size_t)(8192 + s1) * 1024 + d];
  float4 r;
  r.x = w0 * (bf2f(a0.x) + bf2f(a1.x)) + w1 * (bf2f(c0.x) + bf2f(c1.x));
  r.y = w0 * (bf2f(a0.y) + bf2f(a1.y)) + w1 * (bf2f(c0.y) + bf2f(c1.y));
  r.z = w0 * (bf2f(a0.z) + bf2f(a1.z)) + w1 * (bf2f(c0.z) + bf2f(c1.z));
  r.w = w0 * (bf2f(a0.w) + bf2f(a1.w)) + w1 * (bf2f(c0.w) + bf2f(c1.w));
  *(float4*)&out[(size_t)t * 1024 + d] = r;
}

extern "C" void kernel_launch(void* const* d_in, const int* in_sizes, int n_in,
                              void* d_out, int out_size, void* d_ws,
                              size_t ws_size, hipStream_t stream) {
  const float* x = (const float*)d_in[0];
  const float* Wg = (const float*)d_in[1];
  const float* bg = (const float*)d_in[2];
  const float* W1 = (const float*)d_in[3];
  const float* b1 = (const float*)d_in[4];
  const float* W2 = (const float*)d_in[5];
  const float* b2 = (const float*)d_in[6];
  float* out = (float*)d_out;

  char* w = (char*)d_ws;
  int* counts = (int*)w;
  int* offsets = counts + 16;
  int* tok_e = (int*)(w + 1024);
  float* tok_w = (float*)(w + 1024 + 32768);
  int* pair_token = (int*)(w + 1024 + 65536);
  int* tok_slot = (int*)(w + 1024 + 98304);
  unsigned short* xb = (unsigned short*)(w + 256 * 1024);  // 8MB
  unsigned short* P =
      (unsigned short*)(w + 256 * 1024 + 8 * 1024 * 1024);  // 32MB bf16 x2
  char* big = w + 256 * 1024 + 8 * 1024 * 1024 + 32 * 1024 * 1024;
  const size_t avail =
      ws_size - (256 * 1024 + 8 * 1024 * 1024 + 32 * 1024 * 1024);

  // per-chunk: W1t 16384*FC + W2t 16384*FC + H 16384*FC bytes
  int FC = 4096;
  while (FC > 256 && (size_t)FC * 49152 > avail) FC >>= 1;

  unsigned short* W1t = (unsigned short*)big;
  unsigned short* W2t = W1t + (size_t)8 * FC * 1024;
  unsigned short* Hc = W2t + (size_t)8 * 1024 * FC;

  (void)hipMemsetAsync(counts, 0, 64, stream);

  gate_kernel<<<1024, 256, 0, stream>>>(x, Wg, bg, tok_e, tok_w, counts, xb);
  scan_scatter_kernel<<<1, 256, 0, stream>>>(counts, tok_e, offsets,
                                             pair_token, tok_slot);

  const int NT = FC / 128;
  for (int f0 = 0; f0 < 4096; f0 += FC) {
    transW1_kernel<<<dim3(FC / 32, 2, 8), 256, 0, stream>>>(W1, W1t, FC, f0);
    transW2_kernel<<<dim3(32, FC / 256, 8), 256, 0, stream>>>(W2, W2t, FC, f0);
    gemm1_kernel<<<8 * 32 * NT, 256, 0, stream>>>(
        xb, W1t, b1, counts, offsets, pair_token, Hc, FC, f0, NT);
    gemm2_kernel<<<8 * 8 * 32 * 2, 256, 0, stream>>>(
        Hc, W2t, b2, counts, offsets, P, FC, f0 == 0 ? 1 : 0);
  }
  combine_kernel<<<4096, 256, 0, stream>>>(P, tok_slot, tok_w, out);
}